// Round 14
// baseline (392.806 us; speedup 1.0000x reference)
//
#include <hip/hip_runtime.h>

// ---------------------------------------------------------------------------
// RNN-T Joint Network, MI355X (gfx950)
//   f  = enc  @ W_enc^T   : [2048 x 640]
//   g  = pred @ W_pred^T  : [ 512 x 640]
//   out[b,t,u,v] = sum_j tanh(f[bt,j] + g[bu,j]) * W_out[v,j] + b_out[v]
// R14: materialize At = tanh(f(+)g) as fp16 (pre-tiled, 168MB, ~30us) so the
// joint GEMM has ZERO non-gll vmem in its K-loop -> the m201 8-phase
// counted-vmcnt template applies cleanly:
//   256x256 tile, BK=64, 8 waves (2Mx4N), per-wave 128x64, 128KB LDS
//   phase = {8 ds_read, 2 gll, vmcnt(4), barrier, 16 MFMA (setprio), barrier}
//   stage order Ah0,Bh0,Ah1,Bh1 -> every half-tile has 3-4 phases slack;
//   in-flight glls stay 4-6, NEVER drained to 0 in steady state (T4).
// At/Wh pre-tiled [seg16][kc][L][8] -> gll coalesced 1KB/wave AND identity
// conflict-free ds_read (lane*16B).
// ---------------------------------------------------------------------------

typedef _Float16 f16x8 __attribute__((ext_vector_type(8)));
typedef float    f32x4 __attribute__((ext_vector_type(4)));

#define VMW(N) asm volatile("s_waitcnt vmcnt(" #N ")" ::: "memory")

__device__ __forceinline__ float fast_tanh(float x) {
    float e = __builtin_amdgcn_exp2f(x * 2.88539008177792681472f);
    return 1.0f - 2.0f * __builtin_amdgcn_rcpf(e + 1.0f);
}

__device__ __forceinline__ void gll16(const void* g, void* l) {
    __builtin_amdgcn_global_load_lds(
        (const __attribute__((address_space(1))) void*)g,
        (__attribute__((address_space(3))) void*)l, 16, 0, 0);
}

// ---------------------------------------------------------------------------
// Kernel 1: fg GEMM (fp32, exact). W staged transposed -> broadcast reads.
// ---------------------------------------------------------------------------
__global__ __launch_bounds__(256) void fg_kernel(
    const float* __restrict__ enc, const float* __restrict__ pred,
    const float* __restrict__ Wenc, const float* __restrict__ Wpred,
    float* __restrict__ fg)
{
    __shared__ float As[64][36];
    __shared__ float WsT[32][68];

    const int bid = blockIdx.x;
    const int mt = bid / 10;
    const int nt = bid % 10;
    const int m0 = mt * 64;
    const int n0 = nt * 64;

    const float* Aptr;
    const float* Wptr;
    if (m0 < 2048) { Aptr = enc  + (size_t)m0 * 512;          Wptr = Wenc; }
    else           { Aptr = pred + (size_t)(m0 - 2048) * 512; Wptr = Wpred; }

    const int t  = threadIdx.x;
    const int ty = t >> 4;
    const int tx = t & 15;
    const int lr = t >> 2;
    const int lc = (t & 3) * 8;
    const int lane6 = t & 63;
    const int w8    = (t >> 6) * 8;

    float acc[4][4];
#pragma unroll
    for (int i = 0; i < 4; ++i)
#pragma unroll
        for (int j = 0; j < 4; ++j) acc[i][j] = 0.0f;

    for (int k0 = 0; k0 < 512; k0 += 32) {
        __syncthreads();
        {
            const float* sa = Aptr + (size_t)lr * 512 + k0 + lc;
            f32x4 a0 = *(const f32x4*)(sa);
            f32x4 a1 = *(const f32x4*)(sa + 4);
            *(f32x4*)&As[lr][lc]     = a0;
            *(f32x4*)&As[lr][lc + 4] = a1;
            const float* sw = Wptr + (size_t)(n0 + lane6) * 512 + k0 + w8;
            f32x4 w0 = *(const f32x4*)(sw);
            f32x4 w1 = *(const f32x4*)(sw + 4);
#pragma unroll
            for (int j = 0; j < 4; ++j) {
                WsT[w8 + j][lane6]     = w0[j];
                WsT[w8 + 4 + j][lane6] = w1[j];
            }
        }
        __syncthreads();
#pragma unroll
        for (int kk = 0; kk < 32; ++kk) {
            float av[4], bv[4];
#pragma unroll
            for (int i = 0; i < 4; ++i) av[i] = As[ty * 4 + i][kk];
#pragma unroll
            for (int j = 0; j < 4; ++j) bv[j] = WsT[kk][tx * 4 + j];
#pragma unroll
            for (int i = 0; i < 4; ++i)
#pragma unroll
                for (int j = 0; j < 4; ++j)
                    acc[i][j] = fmaf(av[i], bv[j], acc[i][j]);
        }
    }

#pragma unroll
    for (int i = 0; i < 4; ++i) {
        f32x4 v = { acc[i][0], acc[i][1], acc[i][2], acc[i][3] };
        *(f32x4*)&fg[(size_t)(m0 + ty * 4 + i) * 640 + n0 + tx * 4] = v;
    }
}

// ---------------------------------------------------------------------------
// Kernel 2: W_out fp32 [1024][640] -> fp16 tiled [seg][kc][L][8]:
// offset = seg*10240 + kc*512 + L*8, seg=n>>4, kc=k>>5, L=(n&15)+16*((k>>3)&3)
// ---------------------------------------------------------------------------
__global__ __launch_bounds__(256) void wconv_kernel(
    const float* __restrict__ W, _Float16* __restrict__ Wh)
{
    const int tid = blockIdx.x * 256 + threadIdx.x;    // 81920
    const int n   = tid / 80;
    const int c   = tid % 80;
    f32x4 a = *(const f32x4*)(W + (size_t)n * 640 + c * 8);
    f32x4 b = *(const f32x4*)(W + (size_t)n * 640 + c * 8 + 4);
    f16x8 h;
#pragma unroll
    for (int j = 0; j < 4; ++j) { h[j] = (_Float16)a[j]; h[4 + j] = (_Float16)b[j]; }
    const int seg = n >> 4;
    const int kc  = c >> 2;
    const int L   = (n & 15) + 16 * (c & 3);
    *(f16x8*)(Wh + (size_t)seg * 10240 + kc * 512 + L * 8) = h;
}

// ---------------------------------------------------------------------------
// Kernel 2b: At[m][k] = tanh(f[m>>6][k] + g[...][k]) as fp16, SAME tiling as
// Wh: offset = seg*10240 + kc*512 + L*8, seg=m>>4, kc=k>>5,
// L=(m&15)+16*((k>>3)&3).  Thread = (seg*20 + kc)*64 + L -> write is
// lane-contiguous (coalesced); f read is wave-broadcast; g reads are 16
// rows x 64B (L2-hot, g = 1.25 MB).
// ---------------------------------------------------------------------------
__global__ __launch_bounds__(256) void tanh_kernel(
    const float* __restrict__ fg, _Float16* __restrict__ At)
{
    const int tid = blockIdx.x * 256 + threadIdx.x;   // 10,485,760
    const int seg = tid / 1280;
    const int rem = tid - seg * 1280;
    const int kc  = rem >> 6;
    const int L   = rem & 63;
    const int m   = seg * 16 + (L & 15);
    const int k   = kc * 32 + (L >> 4) * 8;

    const float* frow = fg + (size_t)(m >> 6) * 640;
    const float* grow = fg + (size_t)(2048 + ((m >> 14) << 6) + (m & 63)) * 640;

    f32x4 a = *(const f32x4*)(frow + k);
    f32x4 b = *(const f32x4*)(frow + k + 4);
    f32x4 c = *(const f32x4*)(grow + k);
    f32x4 d = *(const f32x4*)(grow + k + 4);
    f16x8 h;
#pragma unroll
    for (int j = 0; j < 4; ++j) {
        h[j]     = (_Float16)fast_tanh(a[j] + c[j]);
        h[4 + j] = (_Float16)fast_tanh(b[j] + d[j]);
    }
    *(f16x8*)(At + (size_t)seg * 10240 + kc * 512 + L * 8) = h;
}

// ---------------------------------------------------------------------------
// Kernel 3: 8-phase counted-vmcnt GEMM (m201 template).
// 256x256 tile, BK=64 (10 K-steps), 512 thr = 8 waves (wm=wid>>2, wn=wid&3),
// per-wave 128x64 C (acc[8][4] f32x4 = 128 AGPR).
// LDS: Ash/Bsh [2 dbuf][2 kc-half][16 seg x 512] = 128 KB total.
// Per K-step, 4 phases (mfh,kh) = (0,0),(1,0),(0,1),(1,1); phase p stages
// half-tile p of K-step t+1 (Ah0,Bh0,Ah1,Bh1); vmcnt(4) per phase keeps
// 4-6 glls in flight permanently (counted-vmcnt trace verified).
// ---------------------------------------------------------------------------
__global__ __launch_bounds__(512, 2) void joint_kernel(
    const _Float16* __restrict__ At, const _Float16* __restrict__ Wh,
    const float* __restrict__ bias, float* __restrict__ out)
{
    __shared__ _Float16 Ash[2][2][8192];
    __shared__ _Float16 Bsh[2][2][8192];

    const int bid = blockIdx.x;                  // 2048
    const int pp  = bid >> 2;                    // 512 m-tiles
    const int mt  = (pp & 7) * 64 + (pp >> 3);   // XCD-chunked (bijective)
    const int ntt = bid & 3;
    const int m0seg = mt * 16;
    const int n0seg = ntt * 16;

    const int t    = threadIdx.x;
    const int lane = t & 63;
    const int wid  = t >> 6;
    const int wm   = wid >> 2;                   // m half (128 rows)
    const int wn   = wid & 3;                    // n quarter (64 cols)
    const int lr   = lane & 15;
    const int lk   = lane >> 4;

    // gll sources: wave stages segs 2*wid, 2*wid+1 of each half-tile
    const _Float16* AsrcW = At + (size_t)(m0seg + 2 * wid) * 10240 + lane * 8;
    const _Float16* BsrcW = Wh + (size_t)(n0seg + 2 * wid) * 10240 + lane * 8;
    const int du0 = (2 * wid) * 512;
    const int du1 = (2 * wid + 1) * 512;

    float bv[4];
#pragma unroll
    for (int nf = 0; nf < 4; ++nf)
        bv[nf] = bias[ntt * 256 + wn * 64 + nf * 16 + lr];

    f32x4 acc[8][4];
#pragma unroll
    for (int i = 0; i < 8; ++i)
#pragma unroll
        for (int j = 0; j < 4; ++j) acc[i][j] = (f32x4){0.f, 0.f, 0.f, 0.f};

    // ---- prologue: stage K-step 0 (kc 0,1) into buf 0, drain, barrier ----
    gll16(AsrcW,               &Ash[0][0][du0]);
    gll16(AsrcW + 10240,       &Ash[0][0][du1]);
    gll16(BsrcW,               &Bsh[0][0][du0]);
    gll16(BsrcW + 10240,       &Bsh[0][0][du1]);
    gll16(AsrcW + 512,         &Ash[0][1][du0]);
    gll16(AsrcW + 10240 + 512, &Ash[0][1][du1]);
    gll16(BsrcW + 512,         &Bsh[0][1][du0]);
    gll16(BsrcW + 10240 + 512, &Bsh[0][1][du1]);
    VMW(0);
    __builtin_amdgcn_s_barrier();

    for (int kt = 0; kt < 9; ++kt) {
        const int b  = kt & 1;
        const int nb = b ^ 1;
        const int kn = (kt + 1) * 2;             // next K-step's kc base

        f16x8 af[4], bf[4];
        // ================= phase 0: (mfh0, kh0), stage A-h0(next) ========
#pragma unroll
        for (int nf = 0; nf < 4; ++nf)
            bf[nf] = *(const f16x8*)&Bsh[b][0][(wn * 4 + nf) * 512 + lane * 8];
#pragma unroll
        for (int i = 0; i < 4; ++i)
            af[i] = *(const f16x8*)&Ash[b][0][(wm * 8 + i) * 512 + lane * 8];
        gll16(AsrcW + kn * 512,         &Ash[nb][0][du0]);
        gll16(AsrcW + 10240 + kn * 512, &Ash[nb][0][du1]);
        VMW(4);
        __builtin_amdgcn_s_barrier();
        __builtin_amdgcn_s_setprio(1);
#pragma unroll
        for (int i = 0; i < 4; ++i)
#pragma unroll
            for (int nf = 0; nf < 4; ++nf)
                acc[i][nf] = __builtin_amdgcn_mfma_f32_16x16x32_f16(
                    af[i], bf[nf], acc[i][nf], 0, 0, 0);
        __builtin_amdgcn_s_setprio(0);
        __builtin_amdgcn_s_barrier();
        // ================= phase 1: (mfh1, kh0), stage B-h0(next) ========
#pragma unroll
        for (int i = 0; i < 4; ++i)
            af[i] = *(const f16x8*)&Ash[b][0][(wm * 8 + 4 + i) * 512 + lane * 8];
        gll16(BsrcW + kn * 512,         &Bsh[nb][0][du0]);
        gll16(BsrcW + 10240 + kn * 512, &Bsh[nb][0][du1]);
        VMW(4);
        __builtin_amdgcn_s_barrier();
        __builtin_amdgcn_s_setprio(1);
#pragma unroll
        for (int i = 0; i < 4; ++i)
#pragma unroll
            for (int nf = 0; nf < 4; ++nf)
                acc[4 + i][nf] = __builtin_amdgcn_mfma_f32_16x16x32_f16(
                    af[i], bf[nf], acc[4 + i][nf], 0, 0, 0);
        __builtin_amdgcn_s_setprio(0);
        __builtin_amdgcn_s_barrier();
        // ================= phase 2: (mfh0, kh1), stage A-h1(next) ========
#pragma unroll
        for (int nf = 0; nf < 4; ++nf)
            bf[nf] = *(const f16x8*)&Bsh[b][1][(wn * 4 + nf) * 512 + lane * 8];
#pragma unroll
        for (int i = 0; i < 4; ++i)
            af[i] = *(const f16x8*)&Ash[b][1][(wm * 8 + i) * 512 + lane * 8];
        gll16(AsrcW + (kn + 1) * 512,         &Ash[nb][1][du0]);
        gll16(AsrcW + 10240 + (kn + 1) * 512, &Ash[nb][1][du1]);
        VMW(4);
        __builtin_amdgcn_s_barrier();
        __builtin_amdgcn_s_setprio(1);
#pragma unroll
        for (int i = 0; i < 4; ++i)
#pragma unroll
            for (int nf = 0; nf < 4; ++nf)
                acc[i][nf] = __builtin_amdgcn_mfma_f32_16x16x32_f16(
                    af[i], bf[nf], acc[i][nf], 0, 0, 0);
        __builtin_amdgcn_s_setprio(0);
        __builtin_amdgcn_s_barrier();
        // ================= phase 3: (mfh1, kh1), stage B-h1(next) ========
#pragma unroll
        for (int i = 0; i < 4; ++i)
            af[i] = *(const f16x8*)&Ash[b][1][(wm * 8 + 4 + i) * 512 + lane * 8];
        gll16(BsrcW + (kn + 1) * 512,         &Bsh[nb][1][du0]);
        gll16(BsrcW + 10240 + (kn + 1) * 512, &Bsh[nb][1][du1]);
        VMW(4);
        __builtin_amdgcn_s_barrier();
        __builtin_amdgcn_s_setprio(1);
#pragma unroll
        for (int i = 0; i < 4; ++i)
#pragma unroll
            for (int nf = 0; nf < 4; ++nf)
                acc[4 + i][nf] = __builtin_amdgcn_mfma_f32_16x16x32_f16(
                    af[i], bf[nf], acc[4 + i][nf], 0, 0, 0);
        __builtin_amdgcn_s_setprio(0);
        __builtin_amdgcn_s_barrier();
    }

    // ---- last K-step (kt=9, buf 1): everything resident, no staging ----
    VMW(0);
    __builtin_amdgcn_s_barrier();
#pragma unroll
    for (int kh = 0; kh < 2; ++kh) {
        f16x8 af[8], bf[4];
#pragma unroll
        for (int nf = 0; nf < 4; ++nf)
            bf[nf] = *(const f16x8*)&Bsh[1][kh][(wn * 4 + nf) * 512 + lane * 8];
#pragma unroll
        for (int i = 0; i < 8; ++i)
            af[i] = *(const f16x8*)&Ash[1][kh][(wm * 8 + i) * 512 + lane * 8];
#pragma unroll
        for (int mf = 0; mf < 8; ++mf)
#pragma unroll
            for (int nf = 0; nf < 4; ++nf)
                acc[mf][nf] = __builtin_amdgcn_mfma_f32_16x16x32_f16(
                    af[mf], bf[nf], acc[mf][nf], 0, 0, 0);
    }

    // ---- epilogue: + bias, cached fp32 stores ----
#pragma unroll
    for (int mf = 0; mf < 8; ++mf) {
#pragma unroll
        for (int rr = 0; rr < 4; ++rr) {
            const int row = mt * 256 + wm * 128 + mf * 16 + lk * 4 + rr;
            float* orow = out + (size_t)row * 1024 + ntt * 256 + wn * 64;
#pragma unroll
            for (int nf = 0; nf < 4; ++nf)
                orow[nf * 16 + lr] = acc[mf][nf][rr] + bv[nf];
        }
    }
}

// ---------------------------------------------------------------------------
extern "C" void kernel_launch(void* const* d_in, const int* in_sizes, int n_in,
                              void* d_out, int out_size, void* d_ws, size_t ws_size,
                              hipStream_t stream) {
    const float* enc   = (const float*)d_in[0];   // [8,256,512]
    const float* pred  = (const float*)d_in[1];   // [8,64,512]
    const float* Wenc  = (const float*)d_in[2];   // [640,512]
    const float* Wpred = (const float*)d_in[3];   // [640,512]
    const float* Wout  = (const float*)d_in[4];   // [1024,640]
    const float* bout  = (const float*)d_in[5];   // [1024]

    float*     fg = (float*)d_ws;                              // 6.55 MB
    _Float16*  Wh = (_Float16*)((char*)d_ws + (8u << 20));     // 1.31 MB
    _Float16*  At = (_Float16*)((char*)d_ws + (16u << 20));    // 167.8 MB

    fg_kernel<<<400, 256, 0, stream>>>(enc, pred, Wenc, Wpred, fg);
    wconv_kernel<<<320, 256, 0, stream>>>(Wout, Wh);
    tanh_kernel<<<40960, 256, 0, stream>>>(fg, At);
    joint_kernel<<<2048, 512, 0, stream>>>(At, Wh, bout, (float*)d_out);
}

// Round 15
// 318.364 us; speedup vs baseline: 1.2338x; 1.2338x over previous
//
#include <hip/hip_runtime.h>

// ---------------------------------------------------------------------------
// RNN-T Joint Network, MI355X (gfx950)
//   f  = enc  @ W_enc^T   : [2048 x 640]
//   g  = pred @ W_pred^T  : [ 512 x 640]
//   out[b,t,u,v] = sum_j tanh(f[bt,j] + g[bu,j]) * W_out[v,j] + b_out[v]
// R15 = R9 base with BN=1024 (FULL N per block), BM=64:
//   - B LDS = full Wh K-slice: 64 segs x 1KB = 64KB/buffer, dbuf = 128KB.
//     Identity-tiled (pre-tiled Wh) -> coalesced gll + zero-conflict reads;
//     each wave's 8 glls stage exactly the 8 segs it consumes.
//   - tanh redundancy x1 (was x2): A-tile 64x32 staged once for all 1024
//     cols; global tanh work halves. f-row is ONE row per block (broadcast).
//   - A: 4 regions, stride 528 f16 (2 mod 8): write quads (2q+r)%8 and read
//     quads (2lk+row)%8 distinct per 8/16-lane group (enumerated, free).
//   - 512 thr = 8 waves, wave tile 64x128 (4x8 frags, 128 AGPR), 2 w/SIMD,
//     1 block/CU (136KB LDS), 20 K-steps, 2 barriers/K-step (best-measured
//     structure), setprio on MFMA, f/g loads before glls.
// ---------------------------------------------------------------------------

typedef _Float16 f16x8 __attribute__((ext_vector_type(8)));
typedef float    f32x4 __attribute__((ext_vector_type(4)));

__device__ __forceinline__ float fast_tanh(float x) {
    float e = __builtin_amdgcn_exp2f(x * 2.88539008177792681472f);
    return 1.0f - 2.0f * __builtin_amdgcn_rcpf(e + 1.0f);
}

__device__ __forceinline__ void gll16(const void* g, void* l) {
    __builtin_amdgcn_global_load_lds(
        (const __attribute__((address_space(1))) void*)g,
        (__attribute__((address_space(3))) void*)l, 16, 0, 0);
}

// ---------------------------------------------------------------------------
// Kernel 1: fg GEMM (fp32, exact). W staged transposed -> broadcast reads.
// ---------------------------------------------------------------------------
__global__ __launch_bounds__(256) void fg_kernel(
    const float* __restrict__ enc, const float* __restrict__ pred,
    const float* __restrict__ Wenc, const float* __restrict__ Wpred,
    float* __restrict__ fg)
{
    __shared__ float As[64][36];
    __shared__ float WsT[32][68];

    const int bid = blockIdx.x;
    const int mt = bid / 10;
    const int nt = bid % 10;
    const int m0 = mt * 64;
    const int n0 = nt * 64;

    const float* Aptr;
    const float* Wptr;
    if (m0 < 2048) { Aptr = enc  + (size_t)m0 * 512;          Wptr = Wenc; }
    else           { Aptr = pred + (size_t)(m0 - 2048) * 512; Wptr = Wpred; }

    const int t  = threadIdx.x;
    const int ty = t >> 4;
    const int tx = t & 15;
    const int lr = t >> 2;
    const int lc = (t & 3) * 8;
    const int lane6 = t & 63;
    const int w8    = (t >> 6) * 8;

    float acc[4][4];
#pragma unroll
    for (int i = 0; i < 4; ++i)
#pragma unroll
        for (int j = 0; j < 4; ++j) acc[i][j] = 0.0f;

    for (int k0 = 0; k0 < 512; k0 += 32) {
        __syncthreads();
        {
            const float* sa = Aptr + (size_t)lr * 512 + k0 + lc;
            f32x4 a0 = *(const f32x4*)(sa);
            f32x4 a1 = *(const f32x4*)(sa + 4);
            *(f32x4*)&As[lr][lc]     = a0;
            *(f32x4*)&As[lr][lc + 4] = a1;
            const float* sw = Wptr + (size_t)(n0 + lane6) * 512 + k0 + w8;
            f32x4 w0 = *(const f32x4*)(sw);
            f32x4 w1 = *(const f32x4*)(sw + 4);
#pragma unroll
            for (int j = 0; j < 4; ++j) {
                WsT[w8 + j][lane6]     = w0[j];
                WsT[w8 + 4 + j][lane6] = w1[j];
            }
        }
        __syncthreads();
#pragma unroll
        for (int kk = 0; kk < 32; ++kk) {
            float av[4], bv[4];
#pragma unroll
            for (int i = 0; i < 4; ++i) av[i] = As[ty * 4 + i][kk];
#pragma unroll
            for (int j = 0; j < 4; ++j) bv[j] = WsT[kk][tx * 4 + j];
#pragma unroll
            for (int i = 0; i < 4; ++i)
#pragma unroll
                for (int j = 0; j < 4; ++j)
                    acc[i][j] = fmaf(av[i], bv[j], acc[i][j]);
        }
    }

#pragma unroll
    for (int i = 0; i < 4; ++i) {
        f32x4 v = { acc[i][0], acc[i][1], acc[i][2], acc[i][3] };
        *(f32x4*)&fg[(size_t)(m0 + ty * 4 + i) * 640 + n0 + tx * 4] = v;
    }
}

// ---------------------------------------------------------------------------
// Kernel 2: W_out fp32 [1024][640] -> fp16 tiled [seg][kc][L][8]:
// offset = seg*10240 + kc*512 + L*8, seg=n>>4, kc=k>>5, L=(n&15)+16*((k>>3)&3)
// -> 64-lane gll at base+lane*8 reads contiguous 1KB; slot L = what the MFMA
// B-fragment wants at lane L (identity, zero-conflict ds_read).
// ---------------------------------------------------------------------------
__global__ __launch_bounds__(256) void wconv_kernel(
    const float* __restrict__ W, _Float16* __restrict__ Wh)
{
    const int tid = blockIdx.x * 256 + threadIdx.x;    // 81920
    const int n   = tid / 80;
    const int c   = tid % 80;
    f32x4 a = *(const f32x4*)(W + (size_t)n * 640 + c * 8);
    f32x4 b = *(const f32x4*)(W + (size_t)n * 640 + c * 8 + 4);
    f16x8 h;
#pragma unroll
    for (int j = 0; j < 4; ++j) { h[j] = (_Float16)a[j]; h[4 + j] = (_Float16)b[j]; }
    const int seg = n >> 4;
    const int kc  = c >> 2;
    const int L   = (n & 15) + 16 * (c & 3);
    *(f16x8*)(Wh + (size_t)seg * 10240 + kc * 512 + L * 8) = h;
}

// ---------------------------------------------------------------------------
// Kernel 3: fused tanh + big GEMM.  BM=64, BN=1024(full), BK=32, 512 thr =
// 8 waves; wave wid owns cols wid*128 (4x8 frags, acc 128 AGPR).
// LDS: Bsh dbuf 2x64KB (identity tiles), Ash dbuf 2x4.2KB -> 136KB, 1 blk/CU.
// Per-iter: f/g loads(next, t<256) -> 8 gll B(next) -> frag reads(cur) ->
//   tanh(next) -> MFMA(cur, setprio) -> ds_write A(next) -> syncthreads.
// ---------------------------------------------------------------------------
__global__ __launch_bounds__(512, 2) void joint_kernel(
    const float* __restrict__ fg, const _Float16* __restrict__ Wh,
    const float* __restrict__ bias, float* __restrict__ out)
{
    __shared__ _Float16 Ash0[4 * 528];      // 4224 B
    __shared__ _Float16 Ash1[4 * 528];
    __shared__ _Float16 Bsh0[64 * 512];     // 64 KB (full N, one K-step)
    __shared__ _Float16 Bsh1[64 * 512];

    const int bid = blockIdx.x;             // 2048 m-tiles
    const int mt  = (bid & 7) * 256 + (bid >> 3);   // XCD-chunked (bijective)
    const int m0  = mt << 6;

    const int t    = threadIdx.x;
    const int lane = t & 63;
    const int wid  = t >> 6;                // 0..7 = n-slice (128 cols)
    const int wn   = wid;
    const int lr   = lane & 15;
    const int lk   = lane >> 4;

    // stage-A mapping (threads t<256): 4 threads per row, 8 k each
    const int r  = (t & 255) >> 2;          // 0..63
    const int q  = t & 3;
    const bool astage = (t < 256);
    const int m  = m0 + r;
    const float* grow = fg + (size_t)(2048 + ((m >> 14) << 6) + (m & 63)) * 640;
    const float* frow = fg + (size_t)mt * 640;    // ONE f-row per block

    // ---- loop-invariant LDS offsets (f16 elems) ----
    int aoff[4];
#pragma unroll
    for (int mf = 0; mf < 4; ++mf)
        aoff[mf] = lk * 528 + (mf * 16 + lr) * 8;
    int boff[8];
#pragma unroll
    for (int nf = 0; nf < 8; ++nf)
        boff[nf] = (wn * 8 + nf) * 512 + lane * 8;   // identity, zero conflict
    const int awoff = q * 528 + r * 8;

    // gll: wave wid stages segs wid*8..+8 (exactly what it consumes)
    const _Float16* gbase = Wh + (size_t)(wid * 8) * 10240 + lane * 8;
    int gdst[8];
#pragma unroll
    for (int i = 0; i < 8; ++i)
        gdst[i] = (wid * 8 + i) * 512;

    f32x4 acc[4][8];
#pragma unroll
    for (int i = 0; i < 4; ++i)
#pragma unroll
        for (int j = 0; j < 8; ++j) acc[i][j] = (f32x4){0.f, 0.f, 0.f, 0.f};

    // ---- prologue: stage k-range 0 into Ash0/Bsh0 ----
    {
#pragma unroll
        for (int i = 0; i < 8; ++i)
            gll16(gbase + (size_t)i * 10240, &Bsh0[gdst[i]]);
        if (astage) {
            f32x4 fv0 = *(const f32x4*)(frow + q * 8);
            f32x4 fv1 = *(const f32x4*)(frow + q * 8 + 4);
            f32x4 gv0 = *(const f32x4*)(grow + q * 8);
            f32x4 gv1 = *(const f32x4*)(grow + q * 8 + 4);
            f16x8 h;
#pragma unroll
            for (int j = 0; j < 4; ++j) {
                h[j]     = (_Float16)fast_tanh(fv0[j] + gv0[j]);
                h[4 + j] = (_Float16)fast_tanh(fv1[j] + gv1[j]);
            }
            *(f16x8*)&Ash0[awoff] = h;
        }
        __syncthreads();
    }

#define JITER_FULL(K0, CA, CB, NA, NB)                                         \
    {                                                                          \
        const int kn_ = (K0) + 32;                                             \
        /* f/g loads FIRST (tanh's vmcnt wait won't drain gll queue) */        \
        f32x4 fv0_, fv1_, gv0_, gv1_;                                          \
        if (astage) {                                                          \
            fv0_ = *(const f32x4*)(frow + kn_ + q * 8);                        \
            fv1_ = *(const f32x4*)(frow + kn_ + q * 8 + 4);                    \
            gv0_ = *(const f32x4*)(grow + kn_ + q * 8);                        \
            gv1_ = *(const f32x4*)(grow + kn_ + q * 8 + 4);                    \
        }                                                                      \
        _Pragma("unroll")                                                      \
        for (int i = 0; i < 8; ++i)                                            \
            gll16(gbase + (size_t)i * 10240 + kn_ * 16, &NB[gdst[i]]);         \
        f16x8 af[4], bf[8];                                                    \
        _Pragma("unroll")                                                      \
        for (int mf = 0; mf < 4; ++mf)                                         \
            af[mf] = *(const f16x8*)&CA[aoff[mf]];                             \
        _Pragma("unroll")                                                      \
        for (int nf = 0; nf < 8; ++nf)                                         \
            bf[nf] = *(const f16x8*)&CB[boff[nf]];                             \
        f16x8 h_;                                                              \
        if (astage) {                                                          \
            _Pragma("unroll")                                                  \
            for (int j = 0; j < 4; ++j) {                                      \
                h_[j]     = (_Float16)fast_tanh(fv0_[j] + gv0_[j]);            \
                h_[4 + j] = (_Float16)fast_tanh(fv1_[j] + gv1_[j]);            \
            }                                                                  \
        }                                                                      \
        __builtin_amdgcn_s_setprio(1);                                         \
        _Pragma("unroll")                                                      \
        for (int mf = 0; mf < 4; ++mf)                                         \
            _Pragma("unroll")                                                  \
            for (int nf = 0; nf < 8; ++nf)                                     \
                acc[mf][nf] = __builtin_amdgcn_mfma_f32_16x16x32_f16(          \
                    af[mf], bf[nf], acc[mf][nf], 0, 0, 0);                     \
        __builtin_amdgcn_s_setprio(0);                                         \
        if (astage)                                                            \
            *(f16x8*)&NA[awoff] = h_;                                          \
        __syncthreads();                                                       \
    }

#define JITER_LAST(CA, CB)                                                     \
    {                                                                          \
        f16x8 af[4], bf[8];                                                    \
        _Pragma("unroll")                                                      \
        for (int mf = 0; mf < 4; ++mf)                                         \
            af[mf] = *(const f16x8*)&CA[aoff[mf]];                             \
        _Pragma("unroll")                                                      \
        for (int nf = 0; nf < 8; ++nf)                                         \
            bf[nf] = *(const f16x8*)&CB[boff[nf]];                             \
        __builtin_amdgcn_s_setprio(1);                                         \
        _Pragma("unroll")                                                      \
        for (int mf = 0; mf < 4; ++mf)                                         \
            _Pragma("unroll")                                                  \
            for (int nf = 0; nf < 8; ++nf)                                     \
                acc[mf][nf] = __builtin_amdgcn_mfma_f32_16x16x32_f16(          \
                    af[mf], bf[nf], acc[mf][nf], 0, 0, 0);                     \
        __builtin_amdgcn_s_setprio(0);                                         \
    }

    for (int kc = 0; kc < 18; kc += 2) {
        JITER_FULL(kc * 32,      Ash0, Bsh0, Ash1, Bsh1);
        JITER_FULL(kc * 32 + 32, Ash1, Bsh1, Ash0, Bsh0);
    }
    JITER_FULL(576, Ash0, Bsh0, Ash1, Bsh1);   // computes k=576, stages 608
    JITER_LAST(Ash1, Bsh1);                    // computes k=608

#undef JITER_FULL
#undef JITER_LAST

    // ---- epilogue: + bias, cached fp32 stores (exact 524 MB total) ----
    float bv[8];
#pragma unroll
    for (int nf = 0; nf < 8; ++nf)
        bv[nf] = bias[wn * 128 + nf * 16 + lr];

#pragma unroll
    for (int mf = 0; mf < 4; ++mf) {
#pragma unroll
        for (int rr = 0; rr < 4; ++rr) {
            const int row = m0 + mf * 16 + lk * 4 + rr;
            float* orow = out + (size_t)row * 1024 + wn * 128;
#pragma unroll
            for (int nf = 0; nf < 8; ++nf)
                orow[nf * 16 + lr] = acc[mf][nf][rr] + bv[nf];
        }
    }
}

// ---------------------------------------------------------------------------
extern "C" void kernel_launch(void* const* d_in, const int* in_sizes, int n_in,
                              void* d_out, int out_size, void* d_ws, size_t ws_size,
                              hipStream_t stream) {
    const float* enc   = (const float*)d_in[0];   // [8,256,512]
    const float* pred  = (const float*)d_in[1];   // [8,64,512]
    const float* Wenc  = (const float*)d_in[2];   // [640,512]
    const float* Wpred = (const float*)d_in[3];   // [640,512]
    const float* Wout  = (const float*)d_in[4];   // [1024,640]
    const float* bout  = (const float*)d_in[5];   // [1024]

    float*     fg = (float*)d_ws;                              // 2560*640 fp32
    _Float16*  Wh = (_Float16*)((char*)d_ws + 2560 * 640 * 4); // tiled 1.25MB

    fg_kernel<<<400, 256, 0, stream>>>(enc, pred, Wenc, Wpred, fg);
    wconv_kernel<<<320, 256, 0, stream>>>(Wout, Wh);
    joint_kernel<<<2048, 512, 0, stream>>>(fg, Wh, bout, (float*)d_out);
}